// Round 8
// baseline (137.055 us; speedup 1.0000x reference)
//
#include <hip/hip_runtime.h>

#define IMG 128
#define PLANE (IMG * IMG)
#define VOLSZ (IMG * IMG * IMG)

// One block per (crop, d_o): 256 threads = 4 waves; lane = w_out; each wave
// handles 16 of the 64 h rows. No LDS: the two w-neighbors (i0', i0'+1) are
// adjacent in memory, so one per-lane global_load_dwordx2 per row fetches
// both. Row bases are wave-uniform (readlane -> SGPR saddr form); the
// per-lane byte offset i0'*4 is loop-invariant. 4 independent gathers +
// ~15 VALU + 1 nontemporal store per 64 outputs.
//
// Index-clamp identity: i0' = min(i0, sz-2), fr' = src - i0'; reference's
// i1-clamp only fires at fr = 0 where fr' = 1 reproduces seg[sz-1] exactly
// -> neighbor always i0'+1, in range, no selects.
__global__ __launch_bounds__(256) void crop_resize_kernel(
    const float* __restrict__ x,      // (4,1,128,128,128) f32
    const int* __restrict__ sizes,    // (4,64) i32
    const int* __restrict__ starts,   // (4,64,3) i32
    float* __restrict__ out)          // (256,64,64,64) f32
{
    // XCD-chunked swizzle (16384 blocks, %8==0 -> bijective)
    int bid  = blockIdx.x;
    int swz  = (bid & 7) * 2048 + (bid >> 3);
    int crop = swz >> 6;
    int d_o  = swz & 63;
    int b    = crop >> 6;

    int sz  = sizes[crop];            // wave-uniform -> scalar
    int s_d = starts[crop * 3 + 0];
    int s_h = starts[crop * 3 + 1];
    int s_w = starts[crop * 3 + 2];

    float szf   = (float)sz;
    float scale = szf * (1.0f / 64.0f);
    float szm1  = szf - 1.0f;
    int   szm2  = sz - 2;

    int lane = threadIdx.x & 63;
    int wid  = __builtin_amdgcn_readfirstlane((int)threadIdx.x >> 6);

    // per-lane (i0', fr') for j = lane — shared by w and h axes
    float srcj = ((float)lane + 0.5f) * scale - 0.5f;
    srcj = fminf(fmaxf(srcj, 0.0f), szm1);
    int   i0p = min((int)srcj, szm2);
    float frp = srcj - (float)i0p;
    float ww = frp, omww = 1.0f - frp;

    int ho0 = (s_h + i0p) * IMG;      // h row offset (broadcast via readlane)

    // d axis (uniform)
    float srcd = ((float)d_o + 0.5f) * scale - 0.5f;
    srcd = fminf(fmaxf(srcd, 0.0f), szm1);
    int   di0p = min((int)srcd, szm2);
    float wd   = srcd - (float)di0p;

    // wave-uniform base of plane d0 row segment start
    const float* prow = x + (long long)b * VOLSZ + (s_d + di0p) * PLANE + s_w;

    float* orow = out + ((long long)crop * 64 + d_o) * 4096 + lane;

    #pragma unroll 4
    for (int it = 0; it < 16; ++it) {
        int   h   = wid + it * 4;
        int   rh0 = __builtin_amdgcn_readlane(ho0, h);          // SGPR
        float wh  = __int_as_float(__builtin_amdgcn_readlane(__float_as_int(frp), h));

        const float* r00 = prow + rh0;                  // (d0,h0)
        const float* r01 = r00 + IMG;                   // (d0,h1)
        const float* r10 = r00 + PLANE;                 // (d1,h0)
        const float* r11 = r00 + PLANE + IMG;           // (d1,h1)

        float2 a = *(const float2*)(r00 + i0p);         // saddr + v_off gathers
        float2 bq = *(const float2*)(r01 + i0p);
        float2 c = *(const float2*)(r10 + i0p);
        float2 d = *(const float2*)(r11 + i0p);

        float v00 = a.x  * omww + a.y  * ww;
        float v01 = bq.x * omww + bq.y * ww;
        float v10 = c.x  * omww + c.y  * ww;
        float v11 = d.x  * omww + d.y  * ww;

        float e0 = v00 + (v01 - v00) * wh;
        float e1 = v10 + (v11 - v10) * wh;
        __builtin_nontemporal_store(e0 + (e1 - e0) * wd, &orow[h * 64]);
    }
}

extern "C" void kernel_launch(void* const* d_in, const int* in_sizes, int n_in,
                              void* d_out, int out_size, void* d_ws, size_t ws_size,
                              hipStream_t stream) {
    const float* x      = (const float*)d_in[0];
    const int*   sizes  = (const int*)d_in[1];
    const int*   starts = (const int*)d_in[2];
    float*       out    = (float*)d_out;

    int blocks = 256 * 64;   // (crop, d_o)
    crop_resize_kernel<<<blocks, 256, 0, stream>>>(x, sizes, starts, out);
}

// Round 9
// 110.815 us; speedup vs baseline: 1.2368x; 1.2368x over previous
//
#include <hip/hip_runtime.h>

#define IMG 128
#define PLANE (IMG * IMG)
#define VOLSZ (IMG * IMG * IMG)

typedef float f4a __attribute__((ext_vector_type(4), aligned(4)));
typedef float f2a __attribute__((ext_vector_type(2), aligned(8)));

// One block per (crop, d_o): 256 threads = 4 waves. Each lane produces TWO
// adjacent w outputs (w = 2wp, 2wp+1, wp = lane&31); half-wave selects one of
// two adjacent h rows (hsel = lane>>5). Per wave-iter: 2 h rows x 64 w = 128
// outputs via 4 dwordx4 gathers + one contiguous 512 B store. NO LDS.
//
// dwordx4 anchor: anc = min(s_w + i0'(w0), IMG-4). Since the reference
// guarantees s_w + i0'(w1) + 1 <= s_w + sz - 1 <= 127 = anc + 3, the load
// covers both lerp pairs at offsets sigma, sigma+delta in {0,1,2} and never
// reads outside the row. Extraction = loop-invariant nested v_cndmask.
//
// Index-clamp identity: i0' = min(i0, sz-2), fr' = src - i0'; reference's
// i1-clamp only fires at fr = 0 where fr' = 1 reproduces seg[sz-1] exactly.
__global__ __launch_bounds__(256) void crop_resize_kernel(
    const float* __restrict__ x,      // (4,1,128,128,128) f32
    const int* __restrict__ sizes,    // (4,64) i32
    const int* __restrict__ starts,   // (4,64,3) i32
    float* __restrict__ out)          // (256,64,64,64) f32
{
    // XCD-chunked swizzle (16384 blocks, %8==0 -> bijective)
    int bid  = blockIdx.x;
    int swz  = (bid & 7) * 2048 + (bid >> 3);
    int crop = swz >> 6;
    int d_o  = swz & 63;
    int b    = crop >> 6;

    int sz  = sizes[crop];            // wave-uniform -> scalar
    int s_d = starts[crop * 3 + 0];
    int s_h = starts[crop * 3 + 1];
    int s_w = starts[crop * 3 + 2];

    float szf   = (float)sz;
    float scale = szf * (1.0f / 64.0f);
    float szm1  = szf - 1.0f;
    int   szm2  = sz - 2;

    int lane = threadIdx.x & 63;
    int wid  = __builtin_amdgcn_readfirstlane((int)threadIdx.x >> 6);
    int wp   = lane & 31;
    int hsel = lane >> 5;

    // ---- axis eval helper (matches reference f32 math) ----
    auto axis = [&](int j, int& i0, float& fr) {
        float src = ((float)j + 0.5f) * scale - 0.5f;
        src = fminf(fmaxf(src, 0.0f), szm1);
        i0 = min((int)src, szm2);
        fr = src - (float)i0;
    };

    // h axis for j = lane (broadcast source)
    int ih; float fh;
    axis(lane, ih, fh);
    int ho0 = (s_h + ih) * IMG;

    // w axis for this lane's pair
    int i00, i01; float fw0, fw1;
    axis(2 * wp,     i00, fw0);
    axis(2 * wp + 1, i01, fw1);
    float omw0 = 1.0f - fw0, omw1 = 1.0f - fw1;

    // anchored load geometry
    int anc   = min(s_w + i00, IMG - 4);   // absolute column of v[0]
    int sig   = s_w + i00 - anc;           // 0..2
    int sigd  = sig + (i01 - i00);         // 0..2 (proven)
    bool a1 = (sig  >= 1), a2 = (sig  >= 2);
    bool b1 = (sigd >= 1), b2 = (sigd >= 2);

    // d axis (uniform)
    int id; float wd_;
    axis(d_o, id, wd_);
    float wd = wd_;

    const float* prow = x + (long long)b * VOLSZ + (s_d + id) * PLANE + anc;

    float* oblk = out + ((long long)crop * 64 + d_o) * 4096 + 2 * wp;

    #pragma unroll
    for (int it = 0; it < 8; ++it) {
        int hA = it * 8 + wid * 2;         // wave covers rows hA, hA+1
        int rA = __builtin_amdgcn_readlane(ho0, hA);
        int rB = __builtin_amdgcn_readlane(ho0, hA + 1);
        float wA = __int_as_float(__builtin_amdgcn_readlane(__float_as_int(fh), hA));
        float wB = __int_as_float(__builtin_amdgcn_readlane(__float_as_int(fh), hA + 1));

        int   rh = hsel ? rB : rA;
        float wh = hsel ? wB : wA;

        const float* r00 = prow + rh;              // (d0, h0)
        f4a va = *(const f4a*)(r00);               // d0 h0
        f4a vb = *(const f4a*)(r00 + IMG);         // d0 h1
        f4a vc = *(const f4a*)(r00 + PLANE);       // d1 h0
        f4a vd = *(const f4a*)(r00 + PLANE + IMG); // d1 h1

        // w-lerp both outputs for each of the 4 rows
        auto wl = [&](f4a v, float& o0, float& o1) {
            float p0 = a1 ? (a2 ? v.z : v.y) : v.x;   // elem sigma
            float p1 = a1 ? (a2 ? v.w : v.z) : v.y;   // sigma+1
            float q0 = b1 ? (b2 ? v.z : v.y) : v.x;   // sigma+delta
            float q1 = b1 ? (b2 ? v.w : v.z) : v.y;   // sigma+delta+1
            o0 = p0 * omw0 + p1 * fw0;
            o1 = q0 * omw1 + q1 * fw1;
        };
        float a0, a1v, b0, b1v, c0, c1v, d0, d1v;
        wl(va, a0, a1v);
        wl(vb, b0, b1v);
        wl(vc, c0, c1v);
        wl(vd, d0, d1v);

        // h-lerp, then d-lerp
        float e00 = a0  + (b0  - a0)  * wh;   // d0, w0
        float e01 = a1v + (b1v - a1v) * wh;   // d0, w1
        float e10 = c0  + (d0  - c0)  * wh;   // d1, w0
        float e11 = c1v + (d1v - c1v) * wh;   // d1, w1

        f2a res;
        res.x = e00 + (e10 - e00) * wd;
        res.y = e01 + (e11 - e01) * wd;

        // lanes 0-31 -> row hA, lanes 32-63 -> row hA+1: contiguous 512 B
        __builtin_nontemporal_store(res, (f2a*)(oblk + (hA + hsel) * 64));
    }
}

extern "C" void kernel_launch(void* const* d_in, const int* in_sizes, int n_in,
                              void* d_out, int out_size, void* d_ws, size_t ws_size,
                              hipStream_t stream) {
    const float* x      = (const float*)d_in[0];
    const int*   sizes  = (const int*)d_in[1];
    const int*   starts = (const int*)d_in[2];
    float*       out    = (float*)d_out;

    int blocks = 256 * 64;   // (crop, d_o)
    crop_resize_kernel<<<blocks, 256, 0, stream>>>(x, sizes, starts, out);
}